// Round 4
// baseline (29.234 us; speedup 1.0000x reference)
//
#include <hip/hip_runtime.h>
#include <math.h>

// Problem constants (match reference setup_inputs)
#define BATCH   8192
#define NCOLS   67      // col0 = user idx, cols 1..66 = item indices
#define DFAC    64      // embedding dim
#define ITEMS   26744
#define THREADS 256
#define WPB     4       // waves per block; 1 batch row per wave
#define NBLOCKS (BATCH / WPB)   // 2048

#define PARTIALS_OFF   0            // 3 planes of NBLOCKS floats = 24 KB
#define ITEMBF16_OFF   32768        // bf16 item table, 26744*64*2 = 3,423,232 B
#define WS_NEEDED      (ITEMBF16_OFF + (size_t)ITEMS * DFAC * 2)

// stable softplus: log(1+exp(t))
__device__ __forceinline__ float softplus_f(float t) {
    return fmaxf(t, 0.f) + log1pf(expf(-fabsf(t)));
}
// jax.nn.log_sigmoid(x) = -softplus(-x)
__device__ __forceinline__ float logsig_f(float x) { return -softplus_f(-x); }

__device__ __forceinline__ float wave_sum(float v) {
    #pragma unroll
    for (int off = 32; off; off >>= 1) v += __shfl_xor(v, off);
    return v;
}
__device__ __forceinline__ float wave_max(float v) {
    #pragma unroll
    for (int off = 32; off; off >>= 1) v = fmaxf(v, __shfl_xor(v, off));
    return v;
}

// f32 -> bf16 (RNE), packed 2-per-uint
__device__ __forceinline__ unsigned bf16rne(float f) {
    unsigned u = __float_as_uint(f);
    return (u + 0x7FFFu + ((u >> 16) & 1u)) >> 16;
}

// Convert item table to bf16 in d_ws. 8 floats per thread -> one uint4 store.
__global__ __launch_bounds__(256) void cvt_items(
    const float* __restrict__ ei, unsigned* __restrict__ out)
{
    const int t = blockIdx.x * 256 + threadIdx.x;
    const int n8 = ITEMS * DFAC / 8;   // 213,952
    if (t >= n8) return;
    const float4 a = *(const float4*)(ei + (size_t)t * 8);
    const float4 b = *(const float4*)(ei + (size_t)t * 8 + 4);
    uint4 o;
    o.x = bf16rne(a.x) | (bf16rne(a.y) << 16);
    o.y = bf16rne(a.z) | (bf16rne(a.w) << 16);
    o.z = bf16rne(b.x) | (bf16rne(b.y) << 16);
    o.w = bf16rne(b.z) | (bf16rne(b.w) << 16);
    *(uint4*)(out + (size_t)t * 4) = o;
}

// One wave per batch row. 8 lanes cooperate per bf16 item row (128B):
// lane hl=lane&7 owns one contiguous uint4 (16B = 8 dims). One load
// instruction covers 8 FULL rows -> 2x64B lines per row, the minimum.
__global__ __launch_bounds__(THREADS) void bpr_main_bf16(
    const int*      __restrict__ one_batch,
    const float*    __restrict__ eu,
    const unsigned* __restrict__ eib,
    float*          __restrict__ partials)
{
    const int lane = threadIdx.x & 63;
    const int wave = threadIdx.x >> 6;
    const int r    = blockIdx.x * WPB + wave;

    const int hl  = lane & 7;   // chunk owner within row (dims hl*8 .. +8)
    const int rg8 = lane >> 3;  // row slot 0..7 within each iteration

    __shared__ float zbuf[WPB][68];
    __shared__ int   ibuf[WPB][68];

    const int* idx = one_batch + r * NCOLS;
    ibuf[wave][lane] = idx[lane];                      // cols 0..63
    if (lane < 3) ibuf[wave][64 + lane] = idx[64 + lane];

    const int uidx = __builtin_amdgcn_readfirstlane(ibuf[wave][0]);

    // user dims [hl*8, hl*8+8) as 2 float4 (replicated 8x across rg8)
    const float4 ua = *(const float4*)(eu + (size_t)uidx * DFAC + hl * 8);
    const float4 ub = *(const float4*)(eu + (size_t)uidx * DFAC + hl * 8 + 4);
    const float uf[8] = {ua.x, ua.y, ua.z, ua.w, ub.x, ub.y, ub.z, ub.w};

    float usq = 0.f;
    #pragma unroll
    for (int e = 0; e < 8; ++e) usq += uf[e] * uf[e];

    float acc_sq = 0.f;

    #pragma unroll
    for (int s = 0; s < 9; ++s) {
        const int  rr    = s * 8 + rg8;     // 0..71; item col = 1+rr
        const bool valid = (rr < 66);
        const int  col   = valid ? 1 + rr : 66;
        const int  ridx  = ibuf[wave][col];

        float pd = 0.f;
        if (valid) {
            const uint4 w = *(const uint4*)(eib + (size_t)ridx * (DFAC / 2) + hl * 4);
            const unsigned wds[4] = {w.x, w.y, w.z, w.w};
            float sq = 0.f;
            #pragma unroll
            for (int e = 0; e < 4; ++e) {
                const float v0 = __uint_as_float(wds[e] << 16);
                const float v1 = __uint_as_float(wds[e] & 0xFFFF0000u);
                pd += v0 * uf[e * 2] + v1 * uf[e * 2 + 1];
                sq += v0 * v0 + v1 * v1;
            }
            acc_sq += sq;
        }
        // reduce dot across the 8-lane row group
        pd += __shfl_xor(pd, 1);
        pd += __shfl_xor(pd, 2);
        pd += __shfl_xor(pd, 4);
        if (valid && hl == 0) zbuf[wave][col] = pd;
    }

    const float z_ai = zbuf[wave][1];
    const float z_aj = zbuf[wave][2];
    const float zak  = zbuf[wave][3 + lane];

    const float one_pn = softplus_f(zak - z_ai) + softplus_f(zak - z_aj);
    const float m6max = wave_max(one_pn);

    float acc_pos = 0.f;
    if (lane == 0) {
        const float dd  = fabsf(z_ai - z_aj);
        acc_pos = logsig_f(fminf(dd, 0.5f) * 2.f - m6max);
    }

    const float acc_m6 = wave_sum(one_pn);
    const float acc_l2 = wave_sum(acc_sq + usq * 0.125f);   // usq replicated 8x

    __shared__ float red[WPB][3];
    if (lane == 0) {
        red[wave][0] = acc_pos; red[wave][1] = acc_m6; red[wave][2] = acc_l2;
    }
    __syncthreads();
    if (threadIdx.x == 0) {
        float p = 0.f, m = 0.f, l = 0.f;
        #pragma unroll
        for (int w = 0; w < WPB; ++w) { p += red[w][0]; m += red[w][1]; l += red[w][2]; }
        partials[blockIdx.x]               = p;   // 3 coalesced planes
        partials[NBLOCKS + blockIdx.x]     = m;
        partials[2 * NBLOCKS + blockIdx.x] = l;
    }
}

// f32 fallback (round-2 proven kernel) if ws_size is too small.
__global__ __launch_bounds__(THREADS) void bpr_main_f32(
    const int*   __restrict__ one_batch,
    const float* __restrict__ eu,
    const float* __restrict__ ei,
    float*       __restrict__ partials)
{
    const int lane = threadIdx.x & 63;
    const int wave = threadIdx.x >> 6;
    const int r    = blockIdx.x * WPB + wave;
    const int rl = lane & 3;
    const int rg = lane >> 2;

    __shared__ float zbuf[WPB][68];
    const int* idx = one_batch + r * NCOLS;
    const int myidx  = idx[lane];
    const int myidx2 = idx[64 + (lane < 3 ? lane : 2)];
    const int uidx = __builtin_amdgcn_readfirstlane(myidx);

    float4 u4[4];
    #pragma unroll
    for (int j = 0; j < 4; ++j)
        u4[j] = *(const float4*)(eu + (size_t)uidx * DFAC + j * 16 + rl * 4);
    float usq = 0.f;
    #pragma unroll
    for (int j = 0; j < 4; ++j)
        usq += u4[j].x*u4[j].x + u4[j].y*u4[j].y + u4[j].z*u4[j].z + u4[j].w*u4[j].w;

    float acc_sq = 0.f;
    #pragma unroll
    for (int s = 0; s < 5; ++s) {
        const int  rr    = s * 16 + rg;
        const bool valid = (rr < 66);
        const int col = valid ? 1 + rr : 66;
        const int ridx = (col < 64) ? __shfl(myidx, col)
                                    : __shfl(myidx2, col - 64);
        float pd = 0.f;
        if (valid) {
            const float* vrow = ei + (size_t)ridx * DFAC + rl * 4;
            float sq = 0.f;
            #pragma unroll
            for (int j = 0; j < 4; ++j) {
                const float4 v4 = *(const float4*)(vrow + j * 16);
                pd += v4.x*u4[j].x + v4.y*u4[j].y + v4.z*u4[j].z + v4.w*u4[j].w;
                sq += v4.x*v4.x + v4.y*v4.y + v4.z*v4.z + v4.w*v4.w;
            }
            acc_sq += sq;
        }
        pd += __shfl_xor(pd, 1);
        pd += __shfl_xor(pd, 2);
        if (valid && rl == 0) zbuf[wave][col] = pd;
    }

    const float z_ai = zbuf[wave][1];
    const float z_aj = zbuf[wave][2];
    const float zak  = zbuf[wave][3 + lane];
    const float one_pn = softplus_f(zak - z_ai) + softplus_f(zak - z_aj);
    const float m6max = wave_max(one_pn);
    float acc_pos = 0.f;
    if (lane == 0) {
        const float dd  = fabsf(z_ai - z_aj);
        acc_pos = logsig_f(fminf(dd, 0.5f) * 2.f - m6max);
    }
    const float acc_m6 = wave_sum(one_pn);
    const float acc_l2 = wave_sum(acc_sq + usq * 0.0625f);

    __shared__ float red[WPB][3];
    if (lane == 0) { red[wave][0] = acc_pos; red[wave][1] = acc_m6; red[wave][2] = acc_l2; }
    __syncthreads();
    if (threadIdx.x == 0) {
        float p = 0.f, m = 0.f, l = 0.f;
        #pragma unroll
        for (int w = 0; w < WPB; ++w) { p += red[w][0]; m += red[w][1]; l += red[w][2]; }
        partials[blockIdx.x]               = p;
        partials[NBLOCKS + blockIdx.x]     = m;
        partials[2 * NBLOCKS + blockIdx.x] = l;
    }
}

__global__ __launch_bounds__(256) void bpr_finalize(
    const float* __restrict__ partials, float* __restrict__ out)
{
    float p = 0.f, m = 0.f, l = 0.f;
    #pragma unroll
    for (int j = 0; j < NBLOCKS / 256; ++j) {   // coalesced plane reads
        const int i = j * 256 + threadIdx.x;
        p += partials[i];
        m += partials[NBLOCKS + i];
        l += partials[2 * NBLOCKS + i];
    }
    p = wave_sum(p); m = wave_sum(m); l = wave_sum(l);

    __shared__ float red[4][3];
    const int lane = threadIdx.x & 63, wave = threadIdx.x >> 6;
    if (lane == 0) { red[wave][0] = p; red[wave][1] = m; red[wave][2] = l; }
    __syncthreads();
    if (threadIdx.x == 0) {
        #pragma unroll
        for (int w = 1; w < 4; ++w) { p += red[w][0]; m += red[w][1]; l += red[w][2]; }
        const float inv = 1.f / (float)BATCH;
        const float l2   = 0.01f * l * inv;
        const float loss = (-p * inv) + m * inv + l2;
        out[0] = loss;
        out[1] = l2;
    }
}

extern "C" void kernel_launch(void* const* d_in, const int* in_sizes, int n_in,
                              void* d_out, int out_size, void* d_ws, size_t ws_size,
                              hipStream_t stream) {
    const int*   one_batch = (const int*)d_in[0];
    const float* eu        = (const float*)d_in[1];
    const float* ei        = (const float*)d_in[2];
    float* out = (float*)d_out;
    float* partials = (float*)((char*)d_ws + PARTIALS_OFF);

    if (ws_size >= WS_NEEDED) {
        unsigned* eib = (unsigned*)((char*)d_ws + ITEMBF16_OFF);
        const int n8 = ITEMS * DFAC / 8;
        cvt_items<<<(n8 + 255) / 256, 256, 0, stream>>>(ei, eib);
        bpr_main_bf16<<<NBLOCKS, THREADS, 0, stream>>>(one_batch, eu, eib, partials);
    } else {
        bpr_main_f32<<<NBLOCKS, THREADS, 0, stream>>>(one_batch, eu, ei, partials);
    }
    bpr_finalize<<<1, 256, 0, stream>>>(partials, out);
}